// Round 1
// baseline (661.325 us; speedup 1.0000x reference)
//
#include <hip/hip_runtime.h>
#include <hip/hip_bf16.h>

// Joiner: out[m, v] = tanh(enc[b_m, t_m, :] + dec[b_m, u_m, :]) @ W[v, :]^T + bias[v]
// M ~ 295k rows, K = 512, V = 500 (padded to 512 in-kernel).
// Strategy: bf16 MFMA GEMM, activations computed once per row into LDS,
// W fragments streamed global->reg (L2-resident), fp32 accumulate.

typedef __attribute__((ext_vector_type(8))) short short8;   // 8 bf16 in 4 VGPRs
typedef __attribute__((ext_vector_type(4))) float f32x4;    // MFMA accumulator

__device__ __forceinline__ unsigned short f2bf(float v) {
    // round-to-nearest-even f32 -> bf16 (inputs are never NaN here)
    unsigned int u = __float_as_uint(v);
    u += 0x7fffu + ((u >> 16) & 1u);
    return (unsigned short)(u >> 16);
}

__device__ __forceinline__ float tanh_fast(float x) {
    // tanh(x) = sign(x) * (1 - e^{-2|x|}) / (1 + e^{-2|x|}); exact at +-inf behavior
    float ax = fabsf(x);
    float t = __expf(-2.0f * ax);
    float r = __fdividef(1.0f - t, 1.0f + t);
    return x < 0.0f ? -r : r;
}

// Convert W (500x512 f32, row-major) -> 512x512 bf16 (rows 500..511 zero) in ws.
__global__ void prep_w_kernel(const float* __restrict__ W, unsigned short* __restrict__ Wbf) {
    const int i = blockIdx.x * blockDim.x + threadIdx.x;  // 65536 threads, 4 elems each
    const int base = i << 2;
    const int n = base >> 9;        // row 0..511
    const int k = base & 511;
    float4 v = make_float4(0.f, 0.f, 0.f, 0.f);
    if (n < 500) v = *reinterpret_cast<const float4*>(W + ((size_t)n << 9) + k);
    uint2 p;
    p.x = (unsigned int)f2bf(v.x) | ((unsigned int)f2bf(v.y) << 16);
    p.y = (unsigned int)f2bf(v.z) | ((unsigned int)f2bf(v.w) << 16);
    *reinterpret_cast<uint2*>(Wbf + base) = p;
}

// Block: 64 rows x 512 cols (500 valid). 256 threads = 4 waves, each wave 64x128.
// LDS: full-K activation tile, bf16, XOR-swizzled to avoid bank conflicts.
template<bool USE_WS>
__global__ __launch_bounds__(256, 2)
void joiner_gemm_kernel(const float* __restrict__ enc, const float* __restrict__ dec,
                        const float* __restrict__ W, const float* __restrict__ bias,
                        const int* __restrict__ b_idx, const int* __restrict__ t_idx,
                        const int* __restrict__ u_idx,
                        const unsigned short* __restrict__ Wbf,
                        float* __restrict__ out, int M)
{
    __shared__ unsigned char Abuf[64 * 512 * 2];   // 64 KB

    const int tid = threadIdx.x;
    const int m0 = blockIdx.x * 64;

    // ---------------- Phase 1: activations -> LDS (bf16) ----------------
    // 2 rows per pass, 128 threads per row -> fully coalesced 2KB/row reads.
    {
        const int rr = tid >> 7;        // 0..1
        const int kq = tid & 127;       // float4 chunk within the 512-wide row
        #pragma unroll 4
        for (int p = 0; p < 32; ++p) {
            const int r = p * 2 + rr;
            const int row = m0 + r;
            uint2 packed = make_uint2(0u, 0u);
            if (row < M) {
                const int bi = b_idx[row], ti = t_idx[row], ui = u_idx[row];
                const float4 e = reinterpret_cast<const float4*>(enc + (((size_t)bi * 512 + ti) << 9))[kq];
                const float4 d = reinterpret_cast<const float4*>(dec + (((size_t)bi * 64 + ui) << 9))[kq];
                const float a0 = tanh_fast(e.x + d.x);
                const float a1 = tanh_fast(e.y + d.y);
                const float a2 = tanh_fast(e.z + d.z);
                const float a3 = tanh_fast(e.w + d.w);
                packed.x = (unsigned int)f2bf(a0) | ((unsigned int)f2bf(a1) << 16);
                packed.y = (unsigned int)f2bf(a2) | ((unsigned int)f2bf(a3) << 16);
            }
            // row-major [64][512] bf16, byte = r*1024 + k*2, XOR-swizzled by row
            const int byteoff = (r * 1024 + kq * 8) ^ ((r & 7) << 4);
            *reinterpret_cast<uint2*>(&Abuf[byteoff]) = packed;
        }
    }
    __syncthreads();

    // ---------------- Phase 2: MFMA GEMM ----------------
    const int lane = tid & 63;
    const int wv   = tid >> 6;          // wave 0..3 -> cols [wv*128, wv*128+128)
    const int l15  = lane & 15;
    const int lk   = lane >> 4;         // 0..3 (k-group of 8)
    const int n_wave = wv * 128;
    const int a_swz  = (l15 & 7) << 4;

    f32x4 acc[4][8];
    #pragma unroll
    for (int mf = 0; mf < 4; ++mf)
        #pragma unroll
        for (int nf = 0; nf < 8; ++nf)
            acc[mf][nf] = (f32x4)(0.0f);

    #pragma unroll 2
    for (int ks = 0; ks < 16; ++ks) {   // K = 16 steps x 32
        // A fragments: lane (l15, lk) reads A[mf*16+l15][ks*32 + lk*8 .. +8]
        short8 a[4];
        #pragma unroll
        for (int mf = 0; mf < 4; ++mf) {
            const int addr = (((mf * 16 + l15) << 10) + ks * 64 + lk * 16) ^ a_swz;
            a[mf] = *reinterpret_cast<const short8*>(&Abuf[addr]);
        }
        #pragma unroll
        for (int nf = 0; nf < 8; ++nf) {
            const int col = n_wave + nf * 16 + l15;
            short8 b;
            if (USE_WS) {
                // bf16 W in workspace: row `col`, k-offset contiguous -> 16B load
                b = *reinterpret_cast<const short8*>(Wbf + (((size_t)col) << 9) + ks * 32 + lk * 8);
            } else {
                float4 w0 = make_float4(0,0,0,0), w1 = make_float4(0,0,0,0);
                if (col < 500) {
                    const float4* wp = reinterpret_cast<const float4*>(W + (((size_t)col) << 9) + ks * 32 + lk * 8);
                    w0 = wp[0]; w1 = wp[1];
                }
                b[0] = (short)f2bf(w0.x); b[1] = (short)f2bf(w0.y);
                b[2] = (short)f2bf(w0.z); b[3] = (short)f2bf(w0.w);
                b[4] = (short)f2bf(w1.x); b[5] = (short)f2bf(w1.y);
                b[6] = (short)f2bf(w1.z); b[7] = (short)f2bf(w1.w);
            }
            #pragma unroll
            for (int mf = 0; mf < 4; ++mf)
                acc[mf][nf] = __builtin_amdgcn_mfma_f32_16x16x32_bf16(a[mf], b, acc[mf][nf], 0, 0, 0);
        }
    }

    // ---------------- Epilogue: bias + masked stores ----------------
    // D mapping (verified layout): col = lane&15, row = (lane>>4)*4 + reg
    #pragma unroll
    for (int nf = 0; nf < 8; ++nf) {
        const int col = n_wave + nf * 16 + l15;
        if (col < 500) {
            const float bv = bias[col];
            #pragma unroll
            for (int mf = 0; mf < 4; ++mf) {
                const int rbase = m0 + mf * 16 + lk * 4;
                #pragma unroll
                for (int j = 0; j < 4; ++j) {
                    const int row = rbase + j;
                    if (row < M)
                        out[(size_t)row * 500 + col] = acc[mf][nf][j] + bv;
                }
            }
        }
    }
}

extern "C" void kernel_launch(void* const* d_in, const int* in_sizes, int n_in,
                              void* d_out, int out_size, void* d_ws, size_t ws_size,
                              hipStream_t stream) {
    const float* enc  = (const float*)d_in[0];
    const float* dec  = (const float*)d_in[1];
    const float* W    = (const float*)d_in[2];
    const float* bias = (const float*)d_in[3];
    const int* bi = (const int*)d_in[4];
    const int* ti = (const int*)d_in[5];
    const int* ui = (const int*)d_in[6];
    float* out = (float*)d_out;

    const int M = in_sizes[4];                 // number of (b,t,u) triples
    const int grid = (M + 63) / 64;

    if (ws_size >= (size_t)(512 * 512 * 2)) {
        prep_w_kernel<<<256, 256, 0, stream>>>(W, (unsigned short*)d_ws);
        joiner_gemm_kernel<true><<<grid, 256, 0, stream>>>(
            enc, dec, W, bias, bi, ti, ui, (const unsigned short*)d_ws, out, M);
    } else {
        joiner_gemm_kernel<false><<<grid, 256, 0, stream>>>(
            enc, dec, W, bias, bi, ti, ui, nullptr, out, M);
    }
}

// Round 3
// 450.385 us; speedup vs baseline: 1.4684x; 1.4684x over previous
//
#include <hip/hip_runtime.h>
#include <hip/hip_bf16.h>

// Joiner: out[m, v] = tanh(enc[b_m, t_m, :] + dec[b_m, u_m, :]) @ W[v, :]^T + bias[v]
// M ~ 295k rows, K = 512, V = 500 (padded to 512).
// bf16 MFMA GEMM; activations staged once per 64-row block into LDS;
// W streamed global->reg with depth-1 software pipeline; coalesced epilogue via LDS.

typedef __attribute__((ext_vector_type(8))) short short8;   // 8 bf16 in 4 VGPRs
typedef __attribute__((ext_vector_type(4))) float f32x4;    // MFMA accumulator

__device__ __forceinline__ unsigned short f2bf(float v) {
    unsigned int u = __float_as_uint(v);
    u += 0x7fffu + ((u >> 16) & 1u);
    return (unsigned short)(u >> 16);
}

__device__ __forceinline__ float tanh_fast(float x) {
    float ax = fabsf(x);
    float t = __expf(-2.0f * ax);
    float r = __fdividef(1.0f - t, 1.0f + t);
    return x < 0.0f ? -r : r;
}

// W (500x512 f32) -> 512x512 bf16 (rows 500..511 zero) in workspace.
__global__ void prep_w_kernel(const float* __restrict__ W, unsigned short* __restrict__ Wbf) {
    const int i = blockIdx.x * blockDim.x + threadIdx.x;
    const int base = i << 2;
    const int n = base >> 9;
    const int k = base & 511;
    float4 v = make_float4(0.f, 0.f, 0.f, 0.f);
    if (n < 500) v = *reinterpret_cast<const float4*>(W + ((size_t)n << 9) + k);
    uint2 p;
    p.x = (unsigned int)f2bf(v.x) | ((unsigned int)f2bf(v.y) << 16);
    p.y = (unsigned int)f2bf(v.z) | ((unsigned int)f2bf(v.w) << 16);
    *reinterpret_cast<uint2*>(Wbf + base) = p;
}

// Block: 64 rows x 512 cols. 256 threads = 4 waves, wave tile 64x128.
template<bool USE_WS>
__global__ __launch_bounds__(256, 2)
void joiner_gemm_kernel(const float* __restrict__ enc, const float* __restrict__ dec,
                        const float* __restrict__ W, const float* __restrict__ bias,
                        const int* __restrict__ b_idx, const int* __restrict__ t_idx,
                        const int* __restrict__ u_idx,
                        const unsigned short* __restrict__ Wbf,
                        float* __restrict__ out, int M)
{
    // Union buffer: phase1/2 = [64][512] bf16 (64KB, XOR-swizzled);
    // epilogue = [64][257] f32 (65792 B, padded to break bank alignment).
    __shared__ unsigned char Abuf[65792];
    __shared__ unsigned int eoffs[64];
    __shared__ unsigned int doffs[64];

    const int tid = threadIdx.x;
    const int m0 = blockIdx.x * 64;

    // ------- Phase 0: gather offsets (kill the idx->addr->load chain) -------
    if (tid < 64) {
        const int rc = min(m0 + tid, M - 1);
        const unsigned bi = (unsigned)b_idx[rc];
        eoffs[tid] = ((bi << 9) + (unsigned)t_idx[rc]) << 9;   // (bi*512+ti)*512
        doffs[tid] = ((bi << 6) + (unsigned)u_idx[rc]) << 9;   // (bi*64 +ui)*512
    }
    __syncthreads();

    // ------- Phase 1: activations -> LDS (bf16), depth-2 pipelined -------
    {
        const int rr = tid >> 7;          // 0..1 : row within pair
        const int kq = tid & 127;         // float4 chunk in 512-wide row
        const int kq4 = kq << 2;

        float4 e0, d0, e1, d1;
        e0 = *reinterpret_cast<const float4*>(enc + eoffs[rr] + kq4);
        d0 = *reinterpret_cast<const float4*>(dec + doffs[rr] + kq4);
        e1 = *reinterpret_cast<const float4*>(enc + eoffs[2 + rr] + kq4);
        d1 = *reinterpret_cast<const float4*>(dec + doffs[2 + rr] + kq4);

        #pragma unroll 4
        for (int p = 0; p < 32; ++p) {
            float4 en = make_float4(0.f, 0.f, 0.f, 0.f);
            float4 dn = make_float4(0.f, 0.f, 0.f, 0.f);
            if (p < 30) {
                const int r2 = (p + 2) * 2 + rr;
                en = *reinterpret_cast<const float4*>(enc + eoffs[r2] + kq4);
                dn = *reinterpret_cast<const float4*>(dec + doffs[r2] + kq4);
            }
            uint2 packed;
            packed.x = (unsigned int)f2bf(tanh_fast(e0.x + d0.x)) |
                       ((unsigned int)f2bf(tanh_fast(e0.y + d0.y)) << 16);
            packed.y = (unsigned int)f2bf(tanh_fast(e0.z + d0.z)) |
                       ((unsigned int)f2bf(tanh_fast(e0.w + d0.w)) << 16);
            const int r = p * 2 + rr;
            const int byteoff = (r * 1024 + kq * 8) ^ ((r & 7) << 4);
            *reinterpret_cast<uint2*>(&Abuf[byteoff]) = packed;
            e0 = e1; d0 = d1; e1 = en; d1 = dn;
        }
    }

    // ------- Phase 2: MFMA GEMM with depth-1 B prefetch -------
    const int lane = tid & 63;
    const int wv   = tid >> 6;
    const int l15  = lane & 15;
    const int lk   = lane >> 4;
    const int n_wave = wv << 7;
    const int a_swz  = (l15 & 7) << 4;

    f32x4 acc[4][8];
    #pragma unroll
    for (int mf = 0; mf < 4; ++mf)
        #pragma unroll
        for (int nf = 0; nf < 8; ++nf)
            acc[mf][nf] = (f32x4)(0.0f);

    const unsigned short* wp = USE_WS ? (Wbf + (((size_t)(n_wave + l15)) << 9) + (lk << 3)) : nullptr;
    const float* wpf = USE_WS ? nullptr : (W + (((size_t)(n_wave + l15)) << 9) + (lk << 3));
    const int colbase = n_wave + l15;

    auto loadB = [&](int ks, int nf) -> short8 {
        if (USE_WS) {
            return *reinterpret_cast<const short8*>(wp + nf * 8192 + ks * 32);
        } else {
            short8 b;
            float4 w0 = make_float4(0,0,0,0), w1 = make_float4(0,0,0,0);
            if (colbase + nf * 16 < 500) {
                const float4* q = reinterpret_cast<const float4*>(wpf + nf * 8192 + ks * 32);
                w0 = q[0]; w1 = q[1];
            }
            b[0] = (short)f2bf(w0.x); b[1] = (short)f2bf(w0.y);
            b[2] = (short)f2bf(w0.z); b[3] = (short)f2bf(w0.w);
            b[4] = (short)f2bf(w1.x); b[5] = (short)f2bf(w1.y);
            b[6] = (short)f2bf(w1.z); b[7] = (short)f2bf(w1.w);
            return b;
        }
    };

    // Initial B tile (issued before the barrier; no LDS dependence).
    short8 Bc[8], Bn[8];
    #pragma unroll
    for (int nf = 0; nf < 8; ++nf) Bc[nf] = loadB(0, nf);

    __syncthreads();

    #pragma unroll 2
    for (int ks = 0; ks < 16; ++ks) {
        if (ks < 15) {
            #pragma unroll
            for (int nf = 0; nf < 8; ++nf) Bn[nf] = loadB(ks + 1, nf);
        }
        short8 a[4];
        #pragma unroll
        for (int mf = 0; mf < 4; ++mf) {
            const int addr = (((mf * 16 + l15) << 10) + ks * 64 + lk * 16) ^ a_swz;
            a[mf] = *reinterpret_cast<const short8*>(&Abuf[addr]);
        }
        __builtin_amdgcn_s_setprio(1);
        #pragma unroll
        for (int mf = 0; mf < 4; ++mf)
            #pragma unroll
            for (int nf = 0; nf < 8; ++nf)
                acc[mf][nf] = __builtin_amdgcn_mfma_f32_16x16x32_bf16(a[mf], Bc[nf], acc[mf][nf], 0, 0, 0);
        __builtin_amdgcn_s_setprio(0);
        #pragma unroll
        for (int nf = 0; nf < 8; ++nf) Bc[nf] = Bn[nf];
    }

    // ------- Epilogue: bias, then coalesced stores via LDS transpose -------
    #pragma unroll
    for (int nf = 0; nf < 8; ++nf) {
        const int col = n_wave + nf * 16 + l15;
        const float bv = (col < 500) ? bias[col] : 0.0f;
        #pragma unroll
        for (int mf = 0; mf < 4; ++mf)
            #pragma unroll
            for (int j = 0; j < 4; ++j)
                acc[mf][nf][j] += bv;
    }

    float* Obuf = reinterpret_cast<float*>(Abuf);   // [64][257] f32
    #pragma unroll
    for (int h = 0; h < 2; ++h) {
        __syncthreads();                  // protects Abuf reuse / pass h-1 reads
        if ((wv >> 1) == h) {
            const int ncol = (wv & 1) << 7;
            #pragma unroll
            for (int mf = 0; mf < 4; ++mf)
                #pragma unroll
                for (int nf = 0; nf < 8; ++nf)
                    #pragma unroll
                    for (int j = 0; j < 4; ++j) {
                        const int r = mf * 16 + lk * 4 + j;
                        Obuf[r * 257 + ncol + nf * 16 + l15] = acc[mf][nf][j];
                    }
        }
        __syncthreads();
        // 64 rows x 64 float4-chunks; each wave stores one full row (1KB contiguous)
        #pragma unroll 4
        for (int i = 0; i < 16; ++i) {
            const int linear = i * 256 + tid;
            const int r  = linear >> 6;
            const int c4 = linear & 63;
            const int row = m0 + r;
            const int col = (h << 8) + (c4 << 2);
            if (row < M && col < 500) {
                const float4 v = *reinterpret_cast<const float4*>(&Obuf[r * 257 + (c4 << 2)]);
                *reinterpret_cast<float4*>(&out[(size_t)row * 500 + col]) = v;
            }
        }
    }
}

extern "C" void kernel_launch(void* const* d_in, const int* in_sizes, int n_in,
                              void* d_out, int out_size, void* d_ws, size_t ws_size,
                              hipStream_t stream) {
    const float* enc  = (const float*)d_in[0];
    const float* dec  = (const float*)d_in[1];
    const float* W    = (const float*)d_in[2];
    const float* bias = (const float*)d_in[3];
    const int* bi = (const int*)d_in[4];
    const int* ti = (const int*)d_in[5];
    const int* ui = (const int*)d_in[6];
    float* out = (float*)d_out;

    const int M = in_sizes[4];
    const int grid = (M + 63) / 64;

    if (ws_size >= (size_t)(512 * 512 * 2)) {
        prep_w_kernel<<<256, 256, 0, stream>>>(W, (unsigned short*)d_ws);
        joiner_gemm_kernel<true><<<grid, 256, 0, stream>>>(
            enc, dec, W, bias, bi, ti, ui, (const unsigned short*)d_ws, out, M);
    } else {
        joiner_gemm_kernel<false><<<grid, 256, 0, stream>>>(
            enc, dec, W, bias, bi, ti, ui, nullptr, out, M);
    }
}